// Round 12
// baseline (378.752 us; speedup 1.0000x reference)
//
#include <hip/hip_runtime.h>
#include <stdint.h>

typedef unsigned short u16;
typedef __attribute__((ext_vector_type(8))) short short8;
typedef __attribute__((ext_vector_type(4))) float f32x4;

typedef __attribute__((address_space(1))) const unsigned int as1_uint;
typedef __attribute__((address_space(3))) unsigned int as3_uint;

#define MFMA16(a, b, c) __builtin_amdgcn_mfma_f32_16x16x32_bf16((a), (b), (c), 0, 0, 0)

__device__ __forceinline__ u16 f2bf(float f) {
  unsigned u = __float_as_uint(f);
  u += 0x7fffu + ((u >> 16) & 1u);
  return (u16)(u >> 16);
}
// packed f32x2 -> bf16x2 (RNE), single HW instruction
__device__ __forceinline__ unsigned pk_bf16(float lo, float hi) {
  unsigned r;
  asm("v_cvt_pk_bf16_f32 %0, %1, %2" : "=v"(r) : "v"(lo), "v"(hi));
  return r;
}
// 2^x, single HW instruction
__device__ __forceinline__ float exp2_hw(float x) {
  float r;
  asm("v_exp_f32 %0, %1" : "=v"(r) : "v"(x));
  return r;
}

#define QSCALE 0.1803368867f  // 0.125 * log2(e): baked into Q so softmax exp = exp2(score)

// ---------------- fused fp32 -> bf16 convert for all 5 tensors ----------------
__global__ void cvt_all(const float* __restrict__ hs, const float* __restrict__ wq,
                        const float* __restrict__ wk, const float* __restrict__ wv,
                        const float* __restrict__ wo, u16* __restrict__ hsb,
                        u16* __restrict__ wqb, u16* __restrict__ wkb,
                        u16* __restrict__ wvb, u16* __restrict__ wob) {
  int i = blockIdx.x * blockDim.x + threadIdx.x;
  const int stride = gridDim.x * blockDim.x;
  for (; i < 3145728; i += stride) {
    const float* src;
    u16* dst;
    int off;
    if (i < 2097152) {
      src = hs; dst = hsb; off = i;
    } else {
      const int j = i - 2097152;
      const int sel = j >> 18;
      off = j & 262143;
      src = (sel == 0) ? wq : (sel == 1) ? wk : (sel == 2) ? wv : wo;
      dst = (sel == 0) ? wqb : (sel == 1) ? wkb : (sel == 2) ? wvb : wob;
    }
    const float4 v = ((const float4*)src)[off];
    ushort4 o;
    o.x = f2bf(v.x); o.y = f2bf(v.y); o.z = f2bf(v.z); o.w = f2bf(v.w);
    ((ushort4*)dst)[off] = o;
  }
}

// ---------------- fused QKV GEMM: C = A(8192,1024) * W(1024,1024)^T ----------------
// grid (64, 24): blockIdx.y>>3 selects {Q,K,V}; (blockIdx.y&7)*128 = N tile.
// Q epilogue bakes QSCALE (softmax scale folded into Q for exp2-only attn).
__global__ __launch_bounds__(256, 2) void gemm_qkv(
    const u16* __restrict__ A, const u16* __restrict__ Wqm,
    const u16* __restrict__ Wkm, const u16* __restrict__ Wvm,
    const float* __restrict__ bq, const float* __restrict__ bk,
    const float* __restrict__ bv, u16* __restrict__ Qo, u16* __restrict__ Ko,
    u16* __restrict__ Vo) {
  constexpr int K = 1024;
  constexpr int NK = K / 32;
  __shared__ u16 Asm[2][128][32];
  __shared__ u16 Bsm[2][128][32];
  __shared__ u16 estg[4][2304];  // per-wave epilogue staging (V:[64][36], QK:[16][72])
  const int tid = threadIdx.x;
  const int w = tid >> 6, l = tid & 63;
  const int sel = blockIdx.y >> 3;
  const u16* Bm = (sel == 0) ? Wqm : (sel == 1) ? Wkm : Wvm;
  const float* bias = (sel == 0) ? bq : (sel == 1) ? bk : bv;
  const int tileM = blockIdx.x * 128, tileN = (blockIdx.y & 7) * 128;
  const int lr = l >> 2;
  const int lk = (l & 3) * 8;

  f32x4 zero = {0.f, 0.f, 0.f, 0.f};
  f32x4 acc[4][4];
#pragma unroll
  for (int i = 0; i < 4; ++i)
#pragma unroll
    for (int j = 0; j < 4; ++j) acc[i][j] = zero;

  const int wm = (w >> 1) * 64, wn = (w & 1) * 64;
  const int fr = l & 15, fk = (l >> 4) * 8;

  auto stage = [&](int buf, int k0) {
#pragma unroll
    for (int j = 0; j < 2; ++j) {
      const int r0 = (j * 4 + w) * 16;
      const u16* srcA = A + (size_t)(tileM + r0 + lr) * K + (k0 + lk);
      __builtin_amdgcn_global_load_lds((as1_uint*)srcA, (as3_uint*)&Asm[buf][r0][0], 16, 0, 0);
      const u16* srcB = Bm + (size_t)(tileN + r0 + lr) * K + (k0 + lk);
      __builtin_amdgcn_global_load_lds((as1_uint*)srcB, (as3_uint*)&Bsm[buf][r0][0], 16, 0, 0);
    }
  };

  stage(0, 0);
  for (int ks = 0; ks < NK; ++ks) {
    const int buf = ks & 1;
    __syncthreads();
    if (ks + 1 < NK) stage(buf ^ 1, (ks + 1) * 32);
    short8 af[4], bfr[4];
#pragma unroll
    for (int i = 0; i < 4; ++i) af[i] = *(const short8*)&Asm[buf][wm + i * 16 + fr][fk];
#pragma unroll
    for (int j = 0; j < 4; ++j) bfr[j] = *(const short8*)&Bsm[buf][wn + j * 16 + fr][fk];
#pragma unroll
    for (int i = 0; i < 4; ++i)
#pragma unroll
      for (int j = 0; j < 4; ++j) acc[i][j] = MFMA16(af[i], bfr[j], acc[i][j]);
  }

  const int fg = (l >> 4) * 4;
  const int hh = (tileN + wn) >> 6;  // each wave's 64 cols = exactly one head
  u16* es = estg[w];

  if (sel == 2) {
    // V -> (b,h,d,s') k-permuted; cvt_pk pairs (r,r+1) are spL-adjacent
#pragma unroll
    for (int c = 0; c < 2; ++c) {
#pragma unroll
      for (int ii = 0; ii < 2; ++ii) {
        const int i = c * 2 + ii;
        const int L0i = ii * 16 + fg;
        const int q = (L0i >> 2) & 7;
        const int pos = (q < 4) ? (2 * q) : (2 * (q - 4) + 1);
#pragma unroll
        for (int j = 0; j < 4; ++j) {
          const float bval = bias[tileN + wn + j * 16 + fr];
          const int d = j * 16 + fr;
          const unsigned w0 = pk_bf16(acc[i][j][0] + bval, acc[i][j][1] + bval);
          const unsigned w1 = pk_bf16(acc[i][j][2] + bval, acc[i][j][3] + bval);
          *(uint2*)&es[d * 36 + pos * 4] = make_uint2(w0, w1);
        }
      }
      const int s0 = tileM + wm + c * 32;
      const int bb = s0 >> 11, sb = s0 & 2047;
#pragma unroll
      for (int rr = 0; rr < 4; ++rr) {
        const int d = rr * 16 + (l >> 2);
        const int seg = (l & 3) * 8;
        short8 vv = *(const short8*)&es[d * 36 + seg];
        *(short8*)&Vo[(((size_t)(bb * 16 + hh)) * 64 + d) * 2048 + sb + seg] = vv;
      }
    }
  } else {
    // Q/K -> (b,h,s,d); Q gets QSCALE baked in
    u16* out = (sel == 0) ? Qo : Ko;
    const float scl = (sel == 0) ? QSCALE : 1.0f;
#pragma unroll
    for (int i = 0; i < 4; ++i) {
#pragma unroll
      for (int j = 0; j < 4; ++j) {
        const float bval = bias[tileN + wn + j * 16 + fr];
#pragma unroll
        for (int r = 0; r < 4; ++r)
          es[(fg + r) * 72 + j * 16 + fr] = f2bf((acc[i][j][r] + bval) * scl);
      }
#pragma unroll
      for (int rr = 0; rr < 2; ++rr) {
        const int row = rr * 8 + (l >> 3);
        const int seg = (l & 7) * 8;
        short8 vv = *(const short8*)&es[row * 72 + seg];
        const int srow = tileM + wm + i * 16 + row;
        const int bb = srow >> 11, s = srow & 2047;
        *(short8*)&out[(((size_t)(bb * 16 + hh)) * 2048 + s) * 64 + seg] = vv;
      }
    }
  }
}

// ---------------- O-projection GEMM: out = ctx(8192,1024) * Wo^T + bo (fp32) ----
__global__ __launch_bounds__(256, 2) void gemm_o(
    const u16* __restrict__ A, const u16* __restrict__ Bm,
    const float* __restrict__ bias, float* __restrict__ out) {
  constexpr int K = 1024;
  constexpr int NK = K / 32;
  __shared__ u16 Asm[2][128][32];
  __shared__ u16 Bsm[2][128][32];
  __shared__ float ostg[4][1088];  // per-wave [16][68] fp32 staging
  const int tid = threadIdx.x;
  const int w = tid >> 6, l = tid & 63;
  const int tileM = blockIdx.x * 128, tileN = blockIdx.y * 128;
  const int lr = l >> 2;
  const int lk = (l & 3) * 8;

  f32x4 zero = {0.f, 0.f, 0.f, 0.f};
  f32x4 acc[4][4];
#pragma unroll
  for (int i = 0; i < 4; ++i)
#pragma unroll
    for (int j = 0; j < 4; ++j) acc[i][j] = zero;

  const int wm = (w >> 1) * 64, wn = (w & 1) * 64;
  const int fr = l & 15, fk = (l >> 4) * 8;

  auto stage = [&](int buf, int k0) {
#pragma unroll
    for (int j = 0; j < 2; ++j) {
      const int r0 = (j * 4 + w) * 16;
      const u16* srcA = A + (size_t)(tileM + r0 + lr) * K + (k0 + lk);
      __builtin_amdgcn_global_load_lds((as1_uint*)srcA, (as3_uint*)&Asm[buf][r0][0], 16, 0, 0);
      const u16* srcB = Bm + (size_t)(tileN + r0 + lr) * K + (k0 + lk);
      __builtin_amdgcn_global_load_lds((as1_uint*)srcB, (as3_uint*)&Bsm[buf][r0][0], 16, 0, 0);
    }
  };

  stage(0, 0);
  for (int ks = 0; ks < NK; ++ks) {
    const int buf = ks & 1;
    __syncthreads();
    if (ks + 1 < NK) stage(buf ^ 1, (ks + 1) * 32);
    short8 af[4], bfr[4];
#pragma unroll
    for (int i = 0; i < 4; ++i) af[i] = *(const short8*)&Asm[buf][wm + i * 16 + fr][fk];
#pragma unroll
    for (int j = 0; j < 4; ++j) bfr[j] = *(const short8*)&Bsm[buf][wn + j * 16 + fr][fk];
#pragma unroll
    for (int i = 0; i < 4; ++i)
#pragma unroll
      for (int j = 0; j < 4; ++j) acc[i][j] = MFMA16(af[i], bfr[j], acc[i][j]);
  }

  const int fg = (l >> 4) * 4;
  float* os = ostg[w];
#pragma unroll
  for (int i = 0; i < 4; ++i) {
#pragma unroll
    for (int j = 0; j < 4; ++j) {
      const float bval = bias[tileN + wn + j * 16 + fr];
#pragma unroll
      for (int r = 0; r < 4; ++r)
        os[(fg + r) * 68 + j * 16 + fr] = acc[i][j][r] + bval;
    }
#pragma unroll
    for (int rr = 0; rr < 4; ++rr) {
      const int row = rr * 4 + (l >> 4);
      const int seg = (l & 15) * 4;
      float4 vv = *(const float4*)&os[row * 68 + seg];
      *(float4*)&out[(size_t)(tileM + wm + i * 16 + row) * 1024 + tileN + wn + seg] = vv;
    }
  }
}

#define VWAIT0() asm volatile("s_waitcnt vmcnt(0)" ::: "memory")
#define VWAIT4() asm volatile("s_waitcnt vmcnt(4)" ::: "memory")
#define LWAIT0() asm volatile("s_waitcnt lgkmcnt(0)" ::: "memory")
#define BAR() asm volatile("s_barrier" ::: "memory")

// ---------------- attention v9: exp2-only softmax, cvt_pk packing, mask fast path ----
__global__ __launch_bounds__(256, 4) void attn_kernel(
    const u16* __restrict__ Qb, const u16* __restrict__ Kb,
    const u16* __restrict__ VTb, const int* __restrict__ amask,
    float* __restrict__ probs, u16* __restrict__ ctx) {
  __shared__ u16 kv[4][4096];                  // pass1: K=kv[0,1], V=kv[2,3]; pass2: K only
  __shared__ float stg[4][1088];               // per-wave [16][68] transpose staging
  __shared__ unsigned long long mbits[32];     // 2048-bit attention mask
  const int tid = threadIdx.x;
  const int w = tid >> 6, l = tid & 63;
  const int L0 = blockIdx.x;
  const int swz = (L0 & 7) * 256 + (L0 >> 3);  // XCD clustering
  const int bh = swz >> 5, qt = swz & 31;
  const int b = bh >> 4, h = bh & 15;
  const int qw = qt * 64 + w * 16;
  const u16* Qp = Qb + ((size_t)bh * 2048 + qw) * 64;
  const u16* Kp = Kb + (size_t)bh * 2048 * 64;
  const u16* Vp = VTb + (size_t)bh * 64 * 2048;
  const int* mrow = amask + b * 2048;
  const int fr = l & 15, fg8 = (l >> 4) * 8, fg4 = (l >> 4) * 4;
  const int cd = l >> 4;
  float* stw = stg[w];

  f32x4 zero = {0.f, 0.f, 0.f, 0.f};
  short8 aq0 = *(const short8*)&Qp[fr * 64 + fg8];
  short8 aq1 = *(const short8*)&Qp[fr * 64 + 32 + fg8];

  auto stageK = [&](int buf, int kt) {
#pragma unroll
    for (int i = 0; i < 2; ++i) {
      const int Lc = tid + i * 256;
      const int row = Lc >> 3, cs = Lc & 7;
      const int c = cs ^ (row & 7);
      const u16* src = Kp + (size_t)(kt * 64 + row) * 64 + c * 8;
      __builtin_amdgcn_global_load_lds((as1_uint*)src, (as3_uint*)&kv[buf][Lc * 8], 16, 0, 0);
    }
  };
  auto stageV = [&](int buf, int kt) {
#pragma unroll
    for (int i = 0; i < 2; ++i) {
      const int Lc = tid + i * 256;
      const int row = Lc >> 3, cs = Lc & 7;
      const int c = cs ^ (row & 7);
      const u16* src = Vp + (size_t)row * 2048 + kt * 64 + c * 8;
      __builtin_amdgcn_global_load_lds((as1_uint*)src, (as3_uint*)&kv[2 + buf][Lc * 8], 16, 0, 0);
    }
  };

  // ---- prologue: mask bitmap + first K/V tile ----
#pragma unroll
  for (int i = 0; i < 8; ++i) {
    const int mv = mrow[tid + i * 256];
    const unsigned long long bal = __ballot(mv != 0);
    if (l == 0) mbits[i * 4 + w] = bal;
  }
  stageK(0, 0);
  stageV(0, 0);
  LWAIT0();
  VWAIT0();
  BAR();

  // ---- pass 1: e=exp2(score) (Q pre-scaled), running sum, PV accumulate ----
  float sa0 = 0.f, sa1 = 0.f, sa2 = 0.f, sa3 = 0.f;
  f32x4 acc4[4];
#pragma unroll
  for (int jd = 0; jd < 4; ++jd) acc4[jd] = zero;

  for (int kt = 0; kt < 32; ++kt) {
    const int buf = kt & 1;
    if (kt + 1 < 32) { stageK(buf ^ 1, kt + 1); stageV(buf ^ 1, kt + 1); }
    const unsigned long long mw = mbits[kt];
    const bool partial = (mw != ~0ull);  // wave-uniform
    float p[4][4];
#pragma unroll
    for (int s = 0; s < 4; ++s) {
      const int r = s * 16 + fr;
      const int c0 = cd ^ (r & 7), c1 = (4 + cd) ^ (r & 7);
      short8 k0 = *(const short8*)&kv[buf][r * 64 + c0 * 8];
      short8 k1 = *(const short8*)&kv[buf][r * 64 + c1 * 8];
      f32x4 a = zero;
      a = MFMA16(k0, aq0, a);
      a = MFMA16(k1, aq1, a);
      p[s][0] = exp2_hw(a[0]);
      p[s][1] = exp2_hw(a[1]);
      p[s][2] = exp2_hw(a[2]);
      p[s][3] = exp2_hw(a[3]);
      if (partial) {
        const unsigned mb = (unsigned)(mw >> (s * 16 + fg4)) & 0xFu;
        if (!(mb & 1u)) p[s][0] = 0.f;
        if (!(mb & 2u)) p[s][1] = 0.f;
        if (!(mb & 4u)) p[s][2] = 0.f;
        if (!(mb & 8u)) p[s][3] = 0.f;
      }
      const float es = (p[s][0] + p[s][1]) + (p[s][2] + p[s][3]);
      if (s == 0) sa0 += es;
      else if (s == 1) sa1 += es;
      else if (s == 2) sa2 += es;
      else sa3 += es;
    }
    // PV with unnormalized e; pb packed via cvt_pk (2 values/instr)
#pragma unroll
    for (int m = 0; m < 2; ++m) {
      union { unsigned u[4]; short8 v; } pbu;
      pbu.u[0] = pk_bf16(p[2 * m][0], p[2 * m][1]);
      pbu.u[1] = pk_bf16(p[2 * m][2], p[2 * m][3]);
      pbu.u[2] = pk_bf16(p[2 * m + 1][0], p[2 * m + 1][1]);
      pbu.u[3] = pk_bf16(p[2 * m + 1][2], p[2 * m + 1][3]);
#pragma unroll
      for (int jd = 0; jd < 4; ++jd) {
        const int ch = (m * 4 + cd) ^ (fr & 7);
        short8 av = *(const short8*)&kv[2 + buf][(jd * 16 + fr) * 64 + ch * 8];
        acc4[jd] = MFMA16(av, pbu.v, acc4[jd]);
      }
    }
    if (kt + 1 < 32) { VWAIT0(); BAR(); }
  }
  float S = (sa0 + sa1) + (sa2 + sa3);
  S += __shfl_xor(S, 16, 64);
  S += __shfl_xor(S, 32, 64);
  const float inv = 1.0f / S;

  // issue first pass-2 K tile now; latency hides under the ctx epilogue
  stageK(0, 0);

  // ---- ctx epilogue: scale by inv, transpose via wave-private staging ----
#pragma unroll
  for (int jd = 0; jd < 4; ++jd) {
    f32x4 sc = acc4[jd];
    sc[0] *= inv; sc[1] *= inv; sc[2] *= inv; sc[3] *= inv;
    *(f32x4*)&stw[fr * 68 + jd * 16 + fg4] = sc;
  }
#pragma unroll
  for (int e = 0; e < 4; ++e) {
    const int row = e * 4 + cd;
    const float4 v = *(const float4*)&stw[row * 68 + fr * 4];
    const unsigned lo = pk_bf16(v.x, v.y);
    const unsigned hi = pk_bf16(v.z, v.w);
    *(uint2*)&ctx[((size_t)b * 2048 + qw + row) * 1024 + h * 64 + fr * 4] = make_uint2(lo, hi);
  }

  VWAIT0();
  BAR();

  // ---- pass 2: recompute scores, normalize, stage+stream probs (K only) ----
  for (int kt = 0; kt < 32; ++kt) {
    const int buf = kt & 1;
    if (kt + 1 < 32) stageK(buf ^ 1, kt + 1);
    const unsigned long long mw = mbits[kt];
    const bool partial = (mw != ~0ull);
#pragma unroll
    for (int s = 0; s < 4; ++s) {
      const int r = s * 16 + fr;
      const int c0 = cd ^ (r & 7), c1 = (4 + cd) ^ (r & 7);
      short8 k0 = *(const short8*)&kv[buf][r * 64 + c0 * 8];
      short8 k1 = *(const short8*)&kv[buf][r * 64 + c1 * 8];
      f32x4 a = zero;
      a = MFMA16(k0, aq0, a);
      a = MFMA16(k1, aq1, a);
      f32x4 pv;
      pv[0] = exp2_hw(a[0]) * inv;
      pv[1] = exp2_hw(a[1]) * inv;
      pv[2] = exp2_hw(a[2]) * inv;
      pv[3] = exp2_hw(a[3]) * inv;
      if (partial) {
        const unsigned mb = (unsigned)(mw >> (s * 16 + fg4)) & 0xFu;
        if (!(mb & 1u)) pv[0] = 0.f;
        if (!(mb & 2u)) pv[1] = 0.f;
        if (!(mb & 4u)) pv[2] = 0.f;
        if (!(mb & 8u)) pv[3] = 0.f;
      }
      *(f32x4*)&stw[fr * 68 + s * 16 + fg4] = pv;  // transpose staging
    }
    // flush probs tile 16x64 (nontemporal, coalesced full lines)
    float* pbase = probs + ((size_t)bh * 2048 + qw) * 2048 + kt * 64;
#pragma unroll
    for (int e = 0; e < 4; ++e) {
      const int row = e * 4 + cd;
      const f32x4 v = *(const f32x4*)&stw[row * 68 + fr * 4];
      __builtin_nontemporal_store(v, (f32x4*)&pbase[(size_t)row * 2048 + fr * 4]);
    }
    if (kt + 1 < 32) { VWAIT4(); BAR(); }  // wait K DMA only; stores stream
  }
}

extern "C" void kernel_launch(void* const* d_in, const int* in_sizes, int n_in,
                              void* d_out, int out_size, void* d_ws, size_t ws_size,
                              hipStream_t stream) {
  const float* hs = (const float*)d_in[0];
  const int* amask = (const int*)d_in[1];
  const float* Wq = (const float*)d_in[2];
  const float* bq = (const float*)d_in[3];
  const float* Wk = (const float*)d_in[4];
  const float* bk = (const float*)d_in[5];
  const float* Wv = (const float*)d_in[6];
  const float* bv = (const float*)d_in[7];
  const float* Wo = (const float*)d_in[8];
  const float* bo = (const float*)d_in[9];
  float* out = (float*)d_out;
  float* probs = out + (size_t)4 * 2048 * 1024;

  char* ws = (char*)d_ws;
  u16* hsb = (u16*)(ws + 0);           // 16 MiB   bf16 hidden (8192 x 1024)
  u16* wqb = (u16*)(ws + 16777216);    // 2 MiB
  u16* wkb = (u16*)(ws + 18874368);
  u16* wvb = (u16*)(ws + 20971520);
  u16* wob = (u16*)(ws + 23068672);
  u16* Qb  = (u16*)(ws + 25165824);    // 16 MiB   (b,h,s,d)  pre-scaled by QSCALE
  u16* Kb  = (u16*)(ws + 41943040);    // 16 MiB   (b,h,s,d)
  u16* VTb = (u16*)(ws + 58720256);    // 16 MiB   (b,h,d,s') k-permuted
  u16* ctx = (u16*)(ws + 75497472);    // 16 MiB   (b*s, h*d)

  cvt_all<<<2048, 256, 0, stream>>>(hs, Wq, Wk, Wv, Wo, hsb, wqb, wkb, wvb, wob);

  gemm_qkv<<<dim3(64, 24), 256, 0, stream>>>(hsb, wqb, wkb, wvb, bq, bk, bv, Qb, Kb, VTb);

  attn_kernel<<<2048, 256, 0, stream>>>(Qb, Kb, VTb, amask, probs, ctx);

  gemm_o<<<dim3(64, 8), 256, 0, stream>>>(ctx, wob, bo, out);
}

// Round 15
// 374.580 us; speedup vs baseline: 1.0111x; 1.0111x over previous
//
#include <hip/hip_runtime.h>
#include <stdint.h>

typedef unsigned short u16;
typedef __attribute__((ext_vector_type(8))) short short8;
typedef __attribute__((ext_vector_type(4))) float f32x4;

typedef __attribute__((address_space(1))) const unsigned int as1_uint;
typedef __attribute__((address_space(3))) unsigned int as3_uint;

#define MFMA16(a, b, c) __builtin_amdgcn_mfma_f32_16x16x32_bf16((a), (b), (c), 0, 0, 0)

__device__ __forceinline__ u16 f2bf(float f) {
  unsigned u = __float_as_uint(f);
  u += 0x7fffu + ((u >> 16) & 1u);
  return (u16)(u >> 16);
}
// packed f32x2 -> bf16x2 (RNE), single HW instruction
__device__ __forceinline__ unsigned pk_bf16(float lo, float hi) {
  unsigned r;
  asm("v_cvt_pk_bf16_f32 %0, %1, %2" : "=v"(r) : "v"(lo), "v"(hi));
  return r;
}
// 2^x, single HW instruction
__device__ __forceinline__ float exp2_hw(float x) {
  float r;
  asm("v_exp_f32 %0, %1" : "=v"(r) : "v"(x));
  return r;
}

#define QSCALE 0.1803368867f  // 0.125 * log2(e): baked into Q so softmax exp = exp2(score)

// ---------------- fused fp32 -> bf16 convert for all 5 tensors ----------------
__global__ void cvt_all(const float* __restrict__ hs, const float* __restrict__ wq,
                        const float* __restrict__ wk, const float* __restrict__ wv,
                        const float* __restrict__ wo, u16* __restrict__ hsb,
                        u16* __restrict__ wqb, u16* __restrict__ wkb,
                        u16* __restrict__ wvb, u16* __restrict__ wob) {
  int i = blockIdx.x * blockDim.x + threadIdx.x;
  const int stride = gridDim.x * blockDim.x;
  for (; i < 3145728; i += stride) {
    const float* src;
    u16* dst;
    int off;
    if (i < 2097152) {
      src = hs; dst = hsb; off = i;
    } else {
      const int j = i - 2097152;
      const int sel = j >> 18;
      off = j & 262143;
      src = (sel == 0) ? wq : (sel == 1) ? wk : (sel == 2) ? wv : wo;
      dst = (sel == 0) ? wqb : (sel == 1) ? wkb : (sel == 2) ? wvb : wob;
    }
    const float4 v = ((const float4*)src)[off];
    ushort4 o;
    o.x = f2bf(v.x); o.y = f2bf(v.y); o.z = f2bf(v.z); o.w = f2bf(v.w);
    ((ushort4*)dst)[off] = o;
  }
}

// ---------------- fused QKV GEMM: C = A(8192,1024) * W(1024,1024)^T ----------------
// grid (64, 24): blockIdx.y>>3 selects {Q,K,V}; (blockIdx.y&7)*128 = N tile.
// Q epilogue bakes QSCALE (softmax scale folded into Q for exp2-only attn).
__global__ __launch_bounds__(256, 2) void gemm_qkv(
    const u16* __restrict__ A, const u16* __restrict__ Wqm,
    const u16* __restrict__ Wkm, const u16* __restrict__ Wvm,
    const float* __restrict__ bq, const float* __restrict__ bk,
    const float* __restrict__ bv, u16* __restrict__ Qo, u16* __restrict__ Ko,
    u16* __restrict__ Vo) {
  constexpr int K = 1024;
  constexpr int NK = K / 32;
  __shared__ u16 Asm[2][128][32];
  __shared__ u16 Bsm[2][128][32];
  __shared__ u16 estg[4][2304];  // per-wave epilogue staging (V:[64][36], QK:[16][72])
  const int tid = threadIdx.x;
  const int w = tid >> 6, l = tid & 63;
  const int sel = blockIdx.y >> 3;
  const u16* Bm = (sel == 0) ? Wqm : (sel == 1) ? Wkm : Wvm;
  const float* bias = (sel == 0) ? bq : (sel == 1) ? bk : bv;
  const int tileM = blockIdx.x * 128, tileN = (blockIdx.y & 7) * 128;
  const int lr = l >> 2;
  const int lk = (l & 3) * 8;

  f32x4 zero = {0.f, 0.f, 0.f, 0.f};
  f32x4 acc[4][4];
#pragma unroll
  for (int i = 0; i < 4; ++i)
#pragma unroll
    for (int j = 0; j < 4; ++j) acc[i][j] = zero;

  const int wm = (w >> 1) * 64, wn = (w & 1) * 64;
  const int fr = l & 15, fk = (l >> 4) * 8;

  auto stage = [&](int buf, int k0) {
#pragma unroll
    for (int j = 0; j < 2; ++j) {
      const int r0 = (j * 4 + w) * 16;
      const u16* srcA = A + (size_t)(tileM + r0 + lr) * K + (k0 + lk);
      __builtin_amdgcn_global_load_lds((as1_uint*)srcA, (as3_uint*)&Asm[buf][r0][0], 16, 0, 0);
      const u16* srcB = Bm + (size_t)(tileN + r0 + lr) * K + (k0 + lk);
      __builtin_amdgcn_global_load_lds((as1_uint*)srcB, (as3_uint*)&Bsm[buf][r0][0], 16, 0, 0);
    }
  };

  stage(0, 0);
  for (int ks = 0; ks < NK; ++ks) {
    const int buf = ks & 1;
    __syncthreads();
    if (ks + 1 < NK) stage(buf ^ 1, (ks + 1) * 32);
    short8 af[4], bfr[4];
#pragma unroll
    for (int i = 0; i < 4; ++i) af[i] = *(const short8*)&Asm[buf][wm + i * 16 + fr][fk];
#pragma unroll
    for (int j = 0; j < 4; ++j) bfr[j] = *(const short8*)&Bsm[buf][wn + j * 16 + fr][fk];
#pragma unroll
    for (int i = 0; i < 4; ++i)
#pragma unroll
      for (int j = 0; j < 4; ++j) acc[i][j] = MFMA16(af[i], bfr[j], acc[i][j]);
  }

  const int fg = (l >> 4) * 4;
  const int hh = (tileN + wn) >> 6;  // each wave's 64 cols = exactly one head
  u16* es = estg[w];

  if (sel == 2) {
    // V -> (b,h,d,s') k-permuted; cvt_pk pairs (r,r+1) are spL-adjacent
#pragma unroll
    for (int c = 0; c < 2; ++c) {
#pragma unroll
      for (int ii = 0; ii < 2; ++ii) {
        const int i = c * 2 + ii;
        const int L0i = ii * 16 + fg;
        const int q = (L0i >> 2) & 7;
        const int pos = (q < 4) ? (2 * q) : (2 * (q - 4) + 1);
#pragma unroll
        for (int j = 0; j < 4; ++j) {
          const float bval = bias[tileN + wn + j * 16 + fr];
          const int d = j * 16 + fr;
          const unsigned w0 = pk_bf16(acc[i][j][0] + bval, acc[i][j][1] + bval);
          const unsigned w1 = pk_bf16(acc[i][j][2] + bval, acc[i][j][3] + bval);
          *(uint2*)&es[d * 36 + pos * 4] = make_uint2(w0, w1);
        }
      }
      const int s0 = tileM + wm + c * 32;
      const int bb = s0 >> 11, sb = s0 & 2047;
#pragma unroll
      for (int rr = 0; rr < 4; ++rr) {
        const int d = rr * 16 + (l >> 2);
        const int seg = (l & 3) * 8;
        short8 vv = *(const short8*)&es[d * 36 + seg];
        *(short8*)&Vo[(((size_t)(bb * 16 + hh)) * 64 + d) * 2048 + sb + seg] = vv;
      }
    }
  } else {
    // Q/K -> (b,h,s,d); Q gets QSCALE baked in
    u16* out = (sel == 0) ? Qo : Ko;
    const float scl = (sel == 0) ? QSCALE : 1.0f;
#pragma unroll
    for (int i = 0; i < 4; ++i) {
#pragma unroll
      for (int j = 0; j < 4; ++j) {
        const float bval = bias[tileN + wn + j * 16 + fr];
#pragma unroll
        for (int r = 0; r < 4; ++r)
          es[(fg + r) * 72 + j * 16 + fr] = f2bf((acc[i][j][r] + bval) * scl);
      }
#pragma unroll
      for (int rr = 0; rr < 2; ++rr) {
        const int row = rr * 8 + (l >> 3);
        const int seg = (l & 7) * 8;
        short8 vv = *(const short8*)&es[row * 72 + seg];
        const int srow = tileM + wm + i * 16 + row;
        const int bb = srow >> 11, s = srow & 2047;
        *(short8*)&out[(((size_t)(bb * 16 + hh)) * 2048 + s) * 64 + seg] = vv;
      }
    }
  }
}

// ---------------- O-projection GEMM: out = ctx(8192,1024) * Wo^T + bo (fp32) ----
__global__ __launch_bounds__(256, 2) void gemm_o(
    const u16* __restrict__ A, const u16* __restrict__ Bm,
    const float* __restrict__ bias, float* __restrict__ out) {
  constexpr int K = 1024;
  constexpr int NK = K / 32;
  __shared__ u16 Asm[2][128][32];
  __shared__ u16 Bsm[2][128][32];
  __shared__ float ostg[4][1088];  // per-wave [16][68] fp32 staging
  const int tid = threadIdx.x;
  const int w = tid >> 6, l = tid & 63;
  const int tileM = blockIdx.x * 128, tileN = blockIdx.y * 128;
  const int lr = l >> 2;
  const int lk = (l & 3) * 8;

  f32x4 zero = {0.f, 0.f, 0.f, 0.f};
  f32x4 acc[4][4];
#pragma unroll
  for (int i = 0; i < 4; ++i)
#pragma unroll
    for (int j = 0; j < 4; ++j) acc[i][j] = zero;

  const int wm = (w >> 1) * 64, wn = (w & 1) * 64;
  const int fr = l & 15, fk = (l >> 4) * 8;

  auto stage = [&](int buf, int k0) {
#pragma unroll
    for (int j = 0; j < 2; ++j) {
      const int r0 = (j * 4 + w) * 16;
      const u16* srcA = A + (size_t)(tileM + r0 + lr) * K + (k0 + lk);
      __builtin_amdgcn_global_load_lds((as1_uint*)srcA, (as3_uint*)&Asm[buf][r0][0], 16, 0, 0);
      const u16* srcB = Bm + (size_t)(tileN + r0 + lr) * K + (k0 + lk);
      __builtin_amdgcn_global_load_lds((as1_uint*)srcB, (as3_uint*)&Bsm[buf][r0][0], 16, 0, 0);
    }
  };

  stage(0, 0);
  for (int ks = 0; ks < NK; ++ks) {
    const int buf = ks & 1;
    __syncthreads();
    if (ks + 1 < NK) stage(buf ^ 1, (ks + 1) * 32);
    short8 af[4], bfr[4];
#pragma unroll
    for (int i = 0; i < 4; ++i) af[i] = *(const short8*)&Asm[buf][wm + i * 16 + fr][fk];
#pragma unroll
    for (int j = 0; j < 4; ++j) bfr[j] = *(const short8*)&Bsm[buf][wn + j * 16 + fr][fk];
#pragma unroll
    for (int i = 0; i < 4; ++i)
#pragma unroll
      for (int j = 0; j < 4; ++j) acc[i][j] = MFMA16(af[i], bfr[j], acc[i][j]);
  }

  const int fg = (l >> 4) * 4;
  float* os = ostg[w];
#pragma unroll
  for (int i = 0; i < 4; ++i) {
#pragma unroll
    for (int j = 0; j < 4; ++j) {
      const float bval = bias[tileN + wn + j * 16 + fr];
#pragma unroll
      for (int r = 0; r < 4; ++r)
        os[(fg + r) * 68 + j * 16 + fr] = acc[i][j][r] + bval;
    }
#pragma unroll
    for (int rr = 0; rr < 4; ++rr) {
      const int row = rr * 4 + (l >> 4);
      const int seg = (l & 15) * 4;
      float4 vv = *(const float4*)&os[row * 68 + seg];
      *(float4*)&out[(size_t)(tileM + wm + i * 16 + row) * 1024 + tileN + wn + seg] = vv;
    }
  }
}

#define VWAIT0() asm volatile("s_waitcnt vmcnt(0)" ::: "memory")
#define VWAIT4() asm volatile("s_waitcnt vmcnt(4)" ::: "memory")
#define LWAIT0() asm volatile("s_waitcnt lgkmcnt(0)" ::: "memory")
#define BAR() asm volatile("s_barrier" ::: "memory")

// ---------------- attention v9: exp2-only softmax, cvt_pk packing, mask fast path ----
__global__ __launch_bounds__(256, 4) void attn_kernel(
    const u16* __restrict__ Qb, const u16* __restrict__ Kb,
    const u16* __restrict__ VTb, const int* __restrict__ amask,
    float* __restrict__ probs, u16* __restrict__ ctx) {
  __shared__ u16 kv[4][4096];                  // pass1: K=kv[0,1], V=kv[2,3]; pass2: K only
  __shared__ float stg[4][1088];               // per-wave [16][68] transpose staging
  __shared__ unsigned long long mbits[32];     // 2048-bit attention mask
  const int tid = threadIdx.x;
  const int w = tid >> 6, l = tid & 63;
  const int L0 = blockIdx.x;
  const int swz = (L0 & 7) * 256 + (L0 >> 3);  // XCD clustering
  const int bh = swz >> 5, qt = swz & 31;
  const int b = bh >> 4, h = bh & 15;
  const int qw = qt * 64 + w * 16;
  const u16* Qp = Qb + ((size_t)bh * 2048 + qw) * 64;
  const u16* Kp = Kb + (size_t)bh * 2048 * 64;
  const u16* Vp = VTb + (size_t)bh * 64 * 2048;
  const int* mrow = amask + b * 2048;
  const int fr = l & 15, fg8 = (l >> 4) * 8, fg4 = (l >> 4) * 4;
  const int cd = l >> 4;
  float* stw = stg[w];

  f32x4 zero = {0.f, 0.f, 0.f, 0.f};
  short8 aq0 = *(const short8*)&Qp[fr * 64 + fg8];
  short8 aq1 = *(const short8*)&Qp[fr * 64 + 32 + fg8];

  auto stageK = [&](int buf, int kt) {
#pragma unroll
    for (int i = 0; i < 2; ++i) {
      const int Lc = tid + i * 256;
      const int row = Lc >> 3, cs = Lc & 7;
      const int c = cs ^ (row & 7);
      const u16* src = Kp + (size_t)(kt * 64 + row) * 64 + c * 8;
      __builtin_amdgcn_global_load_lds((as1_uint*)src, (as3_uint*)&kv[buf][Lc * 8], 16, 0, 0);
    }
  };
  auto stageV = [&](int buf, int kt) {
#pragma unroll
    for (int i = 0; i < 2; ++i) {
      const int Lc = tid + i * 256;
      const int row = Lc >> 3, cs = Lc & 7;
      const int c = cs ^ (row & 7);
      const u16* src = Vp + (size_t)row * 2048 + kt * 64 + c * 8;
      __builtin_amdgcn_global_load_lds((as1_uint*)src, (as3_uint*)&kv[2 + buf][Lc * 8], 16, 0, 0);
    }
  };

  // ---- prologue: mask bitmap + first K/V tile ----
#pragma unroll
  for (int i = 0; i < 8; ++i) {
    const int mv = mrow[tid + i * 256];
    const unsigned long long bal = __ballot(mv != 0);
    if (l == 0) mbits[i * 4 + w] = bal;
  }
  stageK(0, 0);
  stageV(0, 0);
  LWAIT0();
  VWAIT0();
  BAR();

  // ---- pass 1: e=exp2(score) (Q pre-scaled), running sum, PV accumulate ----
  float sa0 = 0.f, sa1 = 0.f, sa2 = 0.f, sa3 = 0.f;
  f32x4 acc4[4];
#pragma unroll
  for (int jd = 0; jd < 4; ++jd) acc4[jd] = zero;

  for (int kt = 0; kt < 32; ++kt) {
    const int buf = kt & 1;
    if (kt + 1 < 32) { stageK(buf ^ 1, kt + 1); stageV(buf ^ 1, kt + 1); }
    const unsigned long long mw = mbits[kt];
    const bool partial = (mw != ~0ull);  // wave-uniform
    float p[4][4];
#pragma unroll
    for (int s = 0; s < 4; ++s) {
      const int r = s * 16 + fr;
      const int c0 = cd ^ (r & 7), c1 = (4 + cd) ^ (r & 7);
      short8 k0 = *(const short8*)&kv[buf][r * 64 + c0 * 8];
      short8 k1 = *(const short8*)&kv[buf][r * 64 + c1 * 8];
      f32x4 a = zero;
      a = MFMA16(k0, aq0, a);
      a = MFMA16(k1, aq1, a);
      p[s][0] = exp2_hw(a[0]);
      p[s][1] = exp2_hw(a[1]);
      p[s][2] = exp2_hw(a[2]);
      p[s][3] = exp2_hw(a[3]);
      if (partial) {
        const unsigned mb = (unsigned)(mw >> (s * 16 + fg4)) & 0xFu;
        if (!(mb & 1u)) p[s][0] = 0.f;
        if (!(mb & 2u)) p[s][1] = 0.f;
        if (!(mb & 4u)) p[s][2] = 0.f;
        if (!(mb & 8u)) p[s][3] = 0.f;
      }
      const float es = (p[s][0] + p[s][1]) + (p[s][2] + p[s][3]);
      if (s == 0) sa0 += es;
      else if (s == 1) sa1 += es;
      else if (s == 2) sa2 += es;
      else sa3 += es;
    }
    // PV with unnormalized e; pb packed via cvt_pk (2 values/instr)
#pragma unroll
    for (int m = 0; m < 2; ++m) {
      union { unsigned u[4]; short8 v; } pbu;
      pbu.u[0] = pk_bf16(p[2 * m][0], p[2 * m][1]);
      pbu.u[1] = pk_bf16(p[2 * m][2], p[2 * m][3]);
      pbu.u[2] = pk_bf16(p[2 * m + 1][0], p[2 * m + 1][1]);
      pbu.u[3] = pk_bf16(p[2 * m + 1][2], p[2 * m + 1][3]);
#pragma unroll
      for (int jd = 0; jd < 4; ++jd) {
        const int ch = (m * 4 + cd) ^ (fr & 7);
        short8 av = *(const short8*)&kv[2 + buf][(jd * 16 + fr) * 64 + ch * 8];
        acc4[jd] = MFMA16(av, pbu.v, acc4[jd]);
      }
    }
    if (kt + 1 < 32) { VWAIT0(); BAR(); }
  }
  float S = (sa0 + sa1) + (sa2 + sa3);
  S += __shfl_xor(S, 16, 64);
  S += __shfl_xor(S, 32, 64);
  const float inv = 1.0f / S;

  // issue first pass-2 K tile now; latency hides under the ctx epilogue
  stageK(0, 0);

  // ---- ctx epilogue: scale by inv, transpose via wave-private staging ----
#pragma unroll
  for (int jd = 0; jd < 4; ++jd) {
    f32x4 sc = acc4[jd];
    sc[0] *= inv; sc[1] *= inv; sc[2] *= inv; sc[3] *= inv;
    *(f32x4*)&stw[fr * 68 + jd * 16 + fg4] = sc;
  }
#pragma unroll
  for (int e = 0; e < 4; ++e) {
    const int row = e * 4 + cd;
    const float4 v = *(const float4*)&stw[row * 68 + fr * 4];
    const unsigned lo = pk_bf16(v.x, v.y);
    const unsigned hi = pk_bf16(v.z, v.w);
    *(uint2*)&ctx[((size_t)b * 2048 + qw + row) * 1024 + h * 64 + fr * 4] = make_uint2(lo, hi);
  }

  VWAIT0();
  BAR();

  // ---- pass 2: recompute scores, normalize, stage+stream probs (K only) ----
  for (int kt = 0; kt < 32; ++kt) {
    const int buf = kt & 1;
    if (kt + 1 < 32) stageK(buf ^ 1, kt + 1);
    const unsigned long long mw = mbits[kt];
    const bool partial = (mw != ~0ull);
#pragma unroll
    for (int s = 0; s < 4; ++s) {
      const int r = s * 16 + fr;
      const int c0 = cd ^ (r & 7), c1 = (4 + cd) ^ (r & 7);
      short8 k0 = *(const short8*)&kv[buf][r * 64 + c0 * 8];
      short8 k1 = *(const short8*)&kv[buf][r * 64 + c1 * 8];
      f32x4 a = zero;
      a = MFMA16(k0, aq0, a);
      a = MFMA16(k1, aq1, a);
      f32x4 pv;
      pv[0] = exp2_hw(a[0]) * inv;
      pv[1] = exp2_hw(a[1]) * inv;
      pv[2] = exp2_hw(a[2]) * inv;
      pv[3] = exp2_hw(a[3]) * inv;
      if (partial) {
        const unsigned mb = (unsigned)(mw >> (s * 16 + fg4)) & 0xFu;
        if (!(mb & 1u)) pv[0] = 0.f;
        if (!(mb & 2u)) pv[1] = 0.f;
        if (!(mb & 4u)) pv[2] = 0.f;
        if (!(mb & 8u)) pv[3] = 0.f;
      }
      *(f32x4*)&stw[fr * 68 + s * 16 + fg4] = pv;  // transpose staging
    }
    // flush probs tile 16x64 (nontemporal, coalesced full lines)
    float* pbase = probs + ((size_t)bh * 2048 + qw) * 2048 + kt * 64;
#pragma unroll
    for (int e = 0; e < 4; ++e) {
      const int row = e * 4 + cd;
      const f32x4 v = *(const f32x4*)&stw[row * 68 + fr * 4];
      __builtin_nontemporal_store(v, (f32x4*)&pbase[(size_t)row * 2048 + fr * 4]);
    }
    if (kt + 1 < 32) { VWAIT4(); BAR(); }  // wait K DMA only; stores stream
  }
}

extern "C" void kernel_launch(void* const* d_in, const int* in_sizes, int n_in,
                              void* d_out, int out_size, void* d_ws, size_t ws_size,
                              hipStream_t stream) {
  const float* hs = (const float*)d_in[0];
  const int* amask = (const int*)d_in[1];
  const float* Wq = (const float*)d_in[2];
  const float* bq = (const float*)d_in[3];
  const float* Wk = (const float*)d_in[4];
  const float* bk = (const float*)d_in[5];
  const float* Wv = (const float*)d_in[6];
  const float* bv = (const float*)d_in[7];
  const float* Wo = (const float*)d_in[8];
  const float* bo = (const float*)d_in[9];
  float* out = (float*)d_out;
  float* probs = out + (size_t)4 * 2048 * 1024;

  char* ws = (char*)d_ws;
  u16* hsb = (u16*)(ws + 0);           // 16 MiB   bf16 hidden (8192 x 1024)
  u16* wqb = (u16*)(ws + 16777216);    // 2 MiB
  u16* wkb = (u16*)(ws + 18874368);
  u16* wvb = (u16*)(ws + 20971520);
  u16* wob = (u16*)(ws + 23068672);
  u16* Qb  = (u16*)(ws + 25165824);    // 16 MiB   (b,h,s,d)  pre-scaled by QSCALE
  u16* Kb  = (u16*)(ws + 41943040);    // 16 MiB   (b,h,s,d)
  u16* VTb = (u16*)(ws + 58720256);    // 16 MiB   (b,h,d,s') k-permuted
  u16* ctx = (u16*)(ws + 75497472);    // 16 MiB   (b*s, h*d)

  cvt_all<<<2048, 256, 0, stream>>>(hs, Wq, Wk, Wv, Wo, hsb, wqb, wkb, wvb, wob);

  gemm_qkv<<<dim3(64, 24), 256, 0, stream>>>(hsb, wqb, wkb, wvb, bq, bk, bv, Qb, Kb, VTb);

  attn_kernel<<<2048, 256, 0, stream>>>(Qb, Kb, VTb, amask, probs, ctx);

  gemm_o<<<dim3(64, 8), 256, 0, stream>>>(ctx, wob, bo, out);
}